// Round 10
// baseline (458.425 us; speedup 1.0000x reference)
//
#include <hip/hip_runtime.h>
#include <hip/hip_bf16.h>

#define B_  2
#define S_  4096
#define D_  512
#define H_  8
#define DH_ 64
#define BH_ 16
#define M_  (B_*S_)   // 8192 rows

typedef __attribute__((ext_vector_type(4))) float f32x4;
typedef __attribute__((ext_vector_type(8))) short s16x8;
typedef __attribute__((ext_vector_type(4))) short s16x4;

#define MFMA(A,Bv,C) __builtin_amdgcn_mfma_f32_16x16x32_bf16(A,Bv,C,0,0,0)

typedef const void __attribute__((address_space(1)))* gas_t;
typedef void __attribute__((address_space(3)))* las_t;
#define GLDS(gp, lp) __builtin_amdgcn_global_load_lds((gas_t)(gp), (las_t)(lp), 16, 0, 0)

// exp(x*0.125) == exp2(x * 0.125*log2(e))
#define EXP_C 0.18033688011112042f

static __device__ __forceinline__ unsigned short f2bf(float f){
    union { __hip_bfloat16 h; unsigned short u; } v;
    v.h = __float2bfloat16(f);           // HW RNE conversion path
    return v.u;
}
static __device__ __forceinline__ float bf2f(unsigned short b){
    union { unsigned int u; float f; } v; v.u = ((unsigned int)b) << 16;
    return v.f;
}

// One launch converts Q (1048576 float4) + 4 weights (65536 float4 each).
__global__ __launch_bounds__(256) void cvt_all(const float* __restrict__ Q,
                                               const float* __restrict__ W0, const float* __restrict__ W1,
                                               const float* __restrict__ W2, const float* __restrict__ W3,
                                               unsigned short* __restrict__ Qd,
                                               unsigned short* __restrict__ D0, unsigned short* __restrict__ D1,
                                               unsigned short* __restrict__ D2, unsigned short* __restrict__ D3){
    int i = blockIdx.x * 256 + threadIdx.x;
    const float* s; unsigned short* d; int off;
    if (i < 1048576){ s = Q; d = Qd; off = i; }
    else {
        int j = i - 1048576;
        int w = j >> 16; off = j & 65535;
        s = (w==0)?W0:(w==1)?W1:(w==2)?W2:W3;
        d = (w==0)?D0:(w==1)?D1:(w==2)?D2:D3;
    }
    float4 v = reinterpret_cast<const float4*>(s)[off];
    ushort4 o;
    o.x = f2bf(v.x); o.y = f2bf(v.y); o.z = f2bf(v.z); o.w = f2bf(v.w);
    reinterpret_cast<ushort4*>(d)[off] = o;
}

// Fused Q/K/V projections. Block computes one 64x64 output tile for all three
// weights (A fragments L1/L2-hot on reuse). q,k -> [bh][s][dh] bf16;
// v -> transposed in LDS -> vT [bh][dh][s] bf16.
__global__ __launch_bounds__(256) void gemm_qkv(const unsigned short* __restrict__ A,
                                                const unsigned short* __restrict__ Wq, const float* __restrict__ bq,
                                                const unsigned short* __restrict__ Wk, const float* __restrict__ bk,
                                                const unsigned short* __restrict__ Wv, const float* __restrict__ bv,
                                                unsigned short* __restrict__ qh, unsigned short* __restrict__ kh,
                                                unsigned short* __restrict__ vT){
    __shared__ unsigned short tile[64][65];
    const int mt = blockIdx.x, nt0 = blockIdx.y;   // mt:[0,128) 64-row tiles, nt0:[0,8) heads
    const int wave = threadIdx.x >> 6, lane = threadIdx.x & 63;
    const int g = lane >> 4, r16 = lane & 15;
    const unsigned short* Ap = A + (size_t)(mt*64 + wave*16 + r16) * 512;
    const int b  = mt >> 6;
    const int s0 = (mt & 63) * 64;
    const int h  = nt0;

    #pragma unroll 1
    for (int w = 0; w < 3; ++w){
        const unsigned short* W = (w==0)?Wq:(w==1)?Wk:Wv;
        const float* bias       = (w==0)?bq:(w==1)?bk:bv;

        f32x4 acc[4];
        #pragma unroll
        for (int i = 0; i < 4; ++i) acc[i] = (f32x4){0.f,0.f,0.f,0.f};

        #pragma unroll
        for (int k0 = 0; k0 < 512; k0 += 64){
            s16x8 a0 = *(const s16x8*)(Ap + k0 + g*8);
            s16x8 a1 = *(const s16x8*)(Ap + k0 + 32 + g*8);
            #pragma unroll
            for (int nt = 0; nt < 4; ++nt){
                const unsigned short* Wp = W + (size_t)(nt0*64 + nt*16 + r16)*512 + k0 + g*8;
                s16x8 b0 = *(const s16x8*)(Wp);
                s16x8 b1 = *(const s16x8*)(Wp + 32);
                acc[nt] = MFMA(a0, b0, acc[nt]);
                acc[nt] = MFMA(a1, b1, acc[nt]);
            }
        }

        if (w < 2){
            unsigned short* dst = (w==0) ? qh : kh;
            #pragma unroll
            for (int nt = 0; nt < 4; ++nt){
                const float bv_ = bias[nt0*64 + nt*16 + r16];
                #pragma unroll
                for (int r = 0; r < 4; ++r){
                    const int s = s0 + wave*16 + g*4 + r;
                    dst[((size_t)(b*H_ + h)*S_ + s)*DH_ + nt*16 + r16] = f2bf(acc[nt][r] + bv_);
                }
            }
        } else {
            #pragma unroll
            for (int nt = 0; nt < 4; ++nt){
                const float bv_ = bias[nt0*64 + nt*16 + r16];
                #pragma unroll
                for (int r = 0; r < 4; ++r)
                    tile[wave*16 + g*4 + r][nt*16 + r16] = f2bf(acc[nt][r] + bv_);
            }
            __syncthreads();
            const int c = threadIdx.x & 63, r4 = threadIdx.x >> 6;
            unsigned short* dst = vT + (size_t)(b*H_ + h)*DH_*S_;
            #pragma unroll
            for (int i = 0; i < 16; ++i){
                const int dh = i*4 + r4;
                dst[(size_t)dh*S_ + s0 + c] = tile[c][dh];
            }
        }
    }
}

// Out-projection: C[m][n] = sum_k A[m][k]*W[n][k] + bias[n], fp32 out.
__global__ __launch_bounds__(256) void gemm_bt(const unsigned short* __restrict__ A,
                                               const unsigned short* __restrict__ W,
                                               const float* __restrict__ bias,
                                               float* __restrict__ dst){
    const int mt = blockIdx.x, nt0 = blockIdx.y;
    const int wave = threadIdx.x >> 6, lane = threadIdx.x & 63;
    const int g = lane >> 4, r16 = lane & 15;
    const unsigned short* Ap = A + (size_t)(mt*64 + wave*16 + r16) * 512;

    f32x4 acc[4];
    #pragma unroll
    for (int i = 0; i < 4; ++i) acc[i] = (f32x4){0.f,0.f,0.f,0.f};

    #pragma unroll
    for (int k0 = 0; k0 < 512; k0 += 64){
        s16x8 a0 = *(const s16x8*)(Ap + k0 + g*8);
        s16x8 a1 = *(const s16x8*)(Ap + k0 + 32 + g*8);
        #pragma unroll
        for (int nt = 0; nt < 4; ++nt){
            const unsigned short* Wp = W + (size_t)(nt0*64 + nt*16 + r16)*512 + k0 + g*8;
            s16x8 b0 = *(const s16x8*)(Wp);
            s16x8 b1 = *(const s16x8*)(Wp + 32);
            acc[nt] = MFMA(a0, b0, acc[nt]);
            acc[nt] = MFMA(a1, b1, acc[nt]);
        }
    }

    #pragma unroll
    for (int nt = 0; nt < 4; ++nt){
        const float bv = bias[nt0*64 + nt*16 + r16];
        #pragma unroll
        for (int r = 0; r < 4; ++r){
            const int orow = mt*64 + wave*16 + g*4 + r;
            dst[(size_t)orow*512 + nt0*64 + nt*16 + r16] = acc[nt][r] + bv;
        }
    }
}

// Fused attention. Block = 128 q rows (8 waves x 16 rows) x all 4096 k.
// Pass 1: 3-deep K ring (counted vmcnt(1), no drains) -> rowsums of exp2.
// Pass 2: K/V double-buffered, recompute scores, stage P (bf16) 2 tiles deep
// per wave, 512B-contiguous attn stores THROUGH L2 (A/B: no nontemporal),
// PV from LDS V tile.
__global__ __launch_bounds__(512, 4) void attn_fused(const unsigned short* __restrict__ qh,
                                                     const unsigned short* __restrict__ kh,
                                                     const unsigned short* __restrict__ vT,
                                                     float* __restrict__ attn,
                                                     unsigned short* __restrict__ ctx){
    __shared__ unsigned short Kb[3*64*64];              // 24 KB (ring-3 / dbuf slots 0,1)
    __shared__ unsigned short Vb[2][64][64];            // 16 KB
    __shared__ __align__(16) unsigned short Pbf[8][16][136];  // 34.8 KB (2-tile)

    // XCD-aware swizzle: 512 blocks, 8 XCDs, 64 consecutive per XCD
    const int lin = blockIdx.y * 32 + blockIdx.x;
    const int nl  = (lin & 7) * 64 + (lin >> 3);
    const int qt  = nl & 31;
    const int bh  = nl >> 5;

    const int wave = threadIdx.x >> 6, lane = threadIdx.x & 63;
    const int g = lane >> 4, r16 = lane & 15;

    const unsigned short* qbase = qh + (size_t)bh*S_*DH_;
    const unsigned short* kbase = kh + (size_t)bh*S_*DH_;
    const unsigned short* vbase = vT + (size_t)bh*DH_*S_;

    // staging: wave stages 8 rows; LDS linear, global source pre-swizzled
    const int tr = wave*8 + (lane >> 3);
    const int cc = (lane & 7) ^ (tr & 7);
    const int stg = tr*64 + (lane & 7)*8;        // LDS short-offset within a slot

    // read-side swizzled chunk offsets (row = nt*16 + r16 -> row&7 == r16&7)
    const int sw = r16 & 7;
    const int c0 = (g ^ sw) * 8;
    const int c1 = ((4 + g) ^ sw) * 8;

    // Q fragment (16 q rows per wave)
    const int qrow = qt*128 + wave*16 + r16;
    s16x8 qa0 = *(const s16x8*)(qbase + (size_t)qrow*DH_ + g*8);
    s16x8 qa1 = *(const s16x8*)(qbase + (size_t)qrow*DH_ + 32 + g*8);

    // ---- pass 1: row sums, 3-deep ring ----
    GLDS(kbase + (size_t)tr*DH_ + cc*8,          Kb + 0*4096 + stg);
    GLDS(kbase + (size_t)(64 + tr)*DH_ + cc*8,   Kb + 1*4096 + stg);

    float lsum[4] = {0.f,0.f,0.f,0.f};
    for (int t = 0; t < 64; ++t){
        if (t == 63) asm volatile("s_waitcnt vmcnt(0)" ::: "memory");
        else         asm volatile("s_waitcnt vmcnt(1)" ::: "memory");
        __builtin_amdgcn_s_barrier();
        __builtin_amdgcn_sched_barrier(0);
        if (t < 62){
            const int s2 = (t + 2) % 3;
            GLDS(kbase + (size_t)((t+2)*64 + tr)*DH_ + cc*8, Kb + s2*4096 + stg);
        }
        __builtin_amdgcn_sched_barrier(0);
        const unsigned short* Kt = Kb + (t % 3)*4096;
        #pragma unroll
        for (int nt = 0; nt < 4; ++nt){
            const int row = nt*16 + r16;
            s16x8 b0 = *(const s16x8*)(Kt + row*64 + c0);
            s16x8 b1 = *(const s16x8*)(Kt + row*64 + c1);
            f32x4 acc = (f32x4){0.f,0.f,0.f,0.f};
            acc = MFMA(qa0, b0, acc);
            acc = MFMA(qa1, b1, acc);
            #pragma unroll
            for (int r = 0; r < 4; ++r)
                lsum[r] += __builtin_amdgcn_exp2f(acc[r]*EXP_C);
        }
    }

    #pragma unroll
    for (int m = 1; m < 16; m <<= 1){
        #pragma unroll
        for (int r = 0; r < 4; ++r) lsum[r] += __shfl_xor(lsum[r], m, 64);
    }
    float inv[4];
    #pragma unroll
    for (int r = 0; r < 4; ++r) inv[r] = 1.0f / lsum[r];

    // ---- handoff: restage K0 + V0 ----
    __builtin_amdgcn_s_barrier();
    __builtin_amdgcn_sched_barrier(0);
    GLDS(kbase + (size_t)tr*DH_ + cc*8, Kb + 0*4096 + stg);
    GLDS(vbase + (size_t)tr*S_  + cc*8, &Vb[0][0][0] + stg);
    asm volatile("s_waitcnt vmcnt(0)" ::: "memory");
    __builtin_amdgcn_s_barrier();
    __builtin_amdgcn_sched_barrier(0);

    // ---- pass 2 ----
    f32x4 oacc[4];
    #pragma unroll
    for (int i = 0; i < 4; ++i) oacc[i] = (f32x4){0.f,0.f,0.f,0.f};

    float* attnW = attn + ((size_t)bh*S_ + qt*128 + wave*16)*S_;
    unsigned short (*Pw)[136] = Pbf[wave];
    const int sl = lane & 31, sh = lane >> 5;

    auto compute_tile = [&](int t){
        const unsigned short* Kt = Kb + (t&1)*4096;
        const unsigned short (*Vt)[64] = Vb[t&1];
        const int cb = (t&1)*64;
        f32x4 pacc[4];
        #pragma unroll
        for (int nt = 0; nt < 4; ++nt){
            const int row = nt*16 + r16;
            s16x8 b0 = *(const s16x8*)(Kt + row*64 + c0);
            s16x8 b1 = *(const s16x8*)(Kt + row*64 + c1);
            f32x4 acc = (f32x4){0.f,0.f,0.f,0.f};
            acc = MFMA(qa0, b0, acc);
            acc = MFMA(qa1, b1, acc);
            pacc[nt] = acc;
        }
        #pragma unroll
        for (int nt = 0; nt < 4; ++nt){
            #pragma unroll
            for (int r = 0; r < 4; ++r){
                float p = __builtin_amdgcn_exp2f(pacc[nt][r]*EXP_C) * inv[r];
                Pw[g*4 + r][cb + nt*16 + r16] = f2bf(p);
            }
        }
        s16x8 pa0 = *(const s16x8*)(&Pw[r16][cb + g*8]);
        s16x8 pa1 = *(const s16x8*)(&Pw[r16][cb + 32 + g*8]);
        #pragma unroll
        for (int nt = 0; nt < 4; ++nt){
            const int row = nt*16 + r16;
            s16x8 v0 = *(const s16x8*)(&Vt[row][c0]);
            s16x8 v1 = *(const s16x8*)(&Vt[row][c1]);
            oacc[nt] = MFMA(pa0, v0, oacc[nt]);
            oacc[nt] = MFMA(pa1, v1, oacc[nt]);
        }
    };

    auto store_pair = [&](int tfirst){   // stores tiles (tfirst, tfirst+1)
        #pragma unroll
        for (int i = 0; i < 8; ++i){
            const int row = i*2 + sh;
            s16x4 pb = *(const s16x4*)(&Pw[row][sl*4]);
            f32x4 o;
            #pragma unroll
            for (int j = 0; j < 4; ++j) o[j] = bf2f((unsigned short)pb[j]);
            *(f32x4*)(attnW + (size_t)row*S_ + tfirst*64 + sl*4) = o;   // A/B: plain store
        }
    };

    // t = 0 (peeled: no stores, full drain)
    GLDS(kbase + (size_t)(1*64 + tr)*DH_ + cc*8, Kb + 1*4096 + stg);
    GLDS(vbase + (size_t)tr*S_ + 1*64 + cc*8,    &Vb[1][0][0] + stg);
    __builtin_amdgcn_sched_barrier(0);
    compute_tile(0);
    asm volatile("s_waitcnt vmcnt(0)" ::: "memory");
    __builtin_amdgcn_s_barrier();
    __builtin_amdgcn_sched_barrier(0);

    for (int t = 1; t < 64; ++t){
        const int nxt = (t + 1) & 63;
        GLDS(kbase + (size_t)(nxt*64 + tr)*DH_ + cc*8, Kb + ((t&1)^1)*4096 + stg);
        GLDS(vbase + (size_t)tr*S_ + nxt*64 + cc*8,    &Vb[(t&1)^1][0][0] + stg);
        __builtin_amdgcn_sched_barrier(0);
        if ((t & 1) == 0){
            store_pair(t - 2);
            __builtin_amdgcn_sched_barrier(0);
        }
        compute_tile(t);
        if (t & 1){
            asm volatile("s_waitcnt vmcnt(0)" ::: "memory");
        } else {
            asm volatile("s_waitcnt vmcnt(8)" ::: "memory");
        }
        __builtin_amdgcn_s_barrier();
        __builtin_amdgcn_sched_barrier(0);
    }
    store_pair(62);

    const int b = bh >> 3, h = bh & 7;
    #pragma unroll
    for (int nt = 0; nt < 4; ++nt){
        #pragma unroll
        for (int r = 0; r < 4; ++r){
            const int qr = qt*128 + wave*16 + g*4 + r;
            ctx[(size_t)(b*S_ + qr)*D_ + h*64 + nt*16 + r16] = f2bf(oacc[nt][r]);
        }
    }
}

extern "C" void kernel_launch(void* const* d_in, const int* in_sizes, int n_in,
                              void* d_out, int out_size, void* d_ws, size_t ws_size,
                              hipStream_t stream){
    const float* Q  = (const float*)d_in[0];
    const float* Wq = (const float*)d_in[1];
    const float* bq = (const float*)d_in[2];
    const float* Wk = (const float*)d_in[3];
    const float* bk = (const float*)d_in[4];
    const float* Wv = (const float*)d_in[5];
    const float* bv = (const float*)d_in[6];
    const float* Wo = (const float*)d_in[7];
    const float* bo = (const float*)d_in[8];

    float* out  = (float*)d_out;                 // [2,4096,512]
    float* attn = out + (size_t)M_*D_;           // [2,8,4096,4096]

    // Pre-attention temporaries live INSIDE the attn output region (dead
    // before attn_fused overwrites it).
    unsigned short* Qbf = (unsigned short*)attn;             // 4.2M elems
    unsigned short* Wqb = Qbf + (size_t)M_*D_;
    unsigned short* Wkb = Wqb + 512*512;
    unsigned short* Wvb = Wkb + 512*512;

    // Persistent scratch in d_ws
    unsigned short* qhb = (unsigned short*)d_ws;             // [BH][S][64]
    unsigned short* khb = qhb + (size_t)BH_*S_*DH_;
    unsigned short* vTb = khb + (size_t)BH_*S_*DH_;          // [BH][64][S]
    unsigned short* ctx = vTb + (size_t)BH_*S_*DH_;          // [M_][512] bf16
    unsigned short* Wob = ctx + (size_t)M_*D_;               // survives attn_fused

    cvt_all<<<dim3(5120), 256, 0, stream>>>(Q, Wq, Wk, Wv, Wo, Qbf, Wqb, Wkb, Wvb, Wob);

    gemm_qkv<<<dim3(M_/64, 8), 256, 0, stream>>>(Qbf, Wqb, bq, Wkb, bk, Wvb, bv,
                                                 qhb, khb, vTb);

    attn_fused<<<dim3(32, BH_), 512, 0, stream>>>(qhb, khb, vTb, attn, ctx);

    gemm_bt<<<dim3(M_/64, D_/64), 256, 0, stream>>>(ctx, Wob, bo, out);
}

// Round 11
// 377.309 us; speedup vs baseline: 1.2150x; 1.2150x over previous
//
#include <hip/hip_runtime.h>
#include <hip/hip_bf16.h>

#define B_  2
#define S_  4096
#define D_  512
#define H_  8
#define DH_ 64
#define BH_ 16
#define M_  (B_*S_)   // 8192 rows

typedef __attribute__((ext_vector_type(4))) float f32x4;
typedef __attribute__((ext_vector_type(8))) short s16x8;
typedef __attribute__((ext_vector_type(4))) short s16x4;

#define MFMA(A,Bv,C) __builtin_amdgcn_mfma_f32_16x16x32_bf16(A,Bv,C,0,0,0)

typedef const void __attribute__((address_space(1)))* gas_t;
typedef void __attribute__((address_space(3)))* las_t;
#define GLDS(gp, lp) __builtin_amdgcn_global_load_lds((gas_t)(gp), (las_t)(lp), 16, 0, 0)

// exp(x*0.125) == exp2(x * 0.125*log2(e))
#define EXP_C 0.18033688011112042f

static __device__ __forceinline__ unsigned short f2bf(float f){
    union { __hip_bfloat16 h; unsigned short u; } v;
    v.h = __float2bfloat16(f);           // HW RNE conversion path
    return v.u;
}
static __device__ __forceinline__ float bf2f(unsigned short b){
    union { unsigned int u; float f; } v; v.u = ((unsigned int)b) << 16;
    return v.f;
}

// One launch converts Q (1048576 float4) + 4 weights (65536 float4 each).
__global__ __launch_bounds__(256) void cvt_all(const float* __restrict__ Q,
                                               const float* __restrict__ W0, const float* __restrict__ W1,
                                               const float* __restrict__ W2, const float* __restrict__ W3,
                                               unsigned short* __restrict__ Qd,
                                               unsigned short* __restrict__ D0, unsigned short* __restrict__ D1,
                                               unsigned short* __restrict__ D2, unsigned short* __restrict__ D3){
    int i = blockIdx.x * 256 + threadIdx.x;
    const float* s; unsigned short* d; int off;
    if (i < 1048576){ s = Q; d = Qd; off = i; }
    else {
        int j = i - 1048576;
        int w = j >> 16; off = j & 65535;
        s = (w==0)?W0:(w==1)?W1:(w==2)?W2:W3;
        d = (w==0)?D0:(w==1)?D1:(w==2)?D2:D3;
    }
    float4 v = reinterpret_cast<const float4*>(s)[off];
    ushort4 o;
    o.x = f2bf(v.x); o.y = f2bf(v.y); o.z = f2bf(v.z); o.w = f2bf(v.w);
    reinterpret_cast<ushort4*>(d)[off] = o;
}

// Fused Q/K/V projections. Block computes one 64x64 output tile for all three
// weights (A fragments L1/L2-hot on reuse). q,k -> [bh][s][dh] bf16;
// v -> transposed in LDS -> vT [bh][dh][s] bf16.
__global__ __launch_bounds__(256) void gemm_qkv(const unsigned short* __restrict__ A,
                                                const unsigned short* __restrict__ Wq, const float* __restrict__ bq,
                                                const unsigned short* __restrict__ Wk, const float* __restrict__ bk,
                                                const unsigned short* __restrict__ Wv, const float* __restrict__ bv,
                                                unsigned short* __restrict__ qh, unsigned short* __restrict__ kh,
                                                unsigned short* __restrict__ vT){
    __shared__ unsigned short tile[64][65];
    const int mt = blockIdx.x, nt0 = blockIdx.y;   // mt:[0,128) 64-row tiles, nt0:[0,8) heads
    const int wave = threadIdx.x >> 6, lane = threadIdx.x & 63;
    const int g = lane >> 4, r16 = lane & 15;
    const unsigned short* Ap = A + (size_t)(mt*64 + wave*16 + r16) * 512;
    const int b  = mt >> 6;
    const int s0 = (mt & 63) * 64;
    const int h  = nt0;

    #pragma unroll 1
    for (int w = 0; w < 3; ++w){
        const unsigned short* W = (w==0)?Wq:(w==1)?Wk:Wv;
        const float* bias       = (w==0)?bq:(w==1)?bk:bv;

        f32x4 acc[4];
        #pragma unroll
        for (int i = 0; i < 4; ++i) acc[i] = (f32x4){0.f,0.f,0.f,0.f};

        #pragma unroll
        for (int k0 = 0; k0 < 512; k0 += 64){
            s16x8 a0 = *(const s16x8*)(Ap + k0 + g*8);
            s16x8 a1 = *(const s16x8*)(Ap + k0 + 32 + g*8);
            #pragma unroll
            for (int nt = 0; nt < 4; ++nt){
                const unsigned short* Wp = W + (size_t)(nt0*64 + nt*16 + r16)*512 + k0 + g*8;
                s16x8 b0 = *(const s16x8*)(Wp);
                s16x8 b1 = *(const s16x8*)(Wp + 32);
                acc[nt] = MFMA(a0, b0, acc[nt]);
                acc[nt] = MFMA(a1, b1, acc[nt]);
            }
        }

        if (w < 2){
            unsigned short* dst = (w==0) ? qh : kh;
            #pragma unroll
            for (int nt = 0; nt < 4; ++nt){
                const float bv_ = bias[nt0*64 + nt*16 + r16];
                #pragma unroll
                for (int r = 0; r < 4; ++r){
                    const int s = s0 + wave*16 + g*4 + r;
                    dst[((size_t)(b*H_ + h)*S_ + s)*DH_ + nt*16 + r16] = f2bf(acc[nt][r] + bv_);
                }
            }
        } else {
            #pragma unroll
            for (int nt = 0; nt < 4; ++nt){
                const float bv_ = bias[nt0*64 + nt*16 + r16];
                #pragma unroll
                for (int r = 0; r < 4; ++r)
                    tile[wave*16 + g*4 + r][nt*16 + r16] = f2bf(acc[nt][r] + bv_);
            }
            __syncthreads();
            const int c = threadIdx.x & 63, r4 = threadIdx.x >> 6;
            unsigned short* dst = vT + (size_t)(b*H_ + h)*DH_*S_;
            #pragma unroll
            for (int i = 0; i < 16; ++i){
                const int dh = i*4 + r4;
                dst[(size_t)dh*S_ + s0 + c] = tile[c][dh];
            }
        }
    }
}

// Out-projection: C[m][n] = sum_k A[m][k]*W[n][k] + bias[n], fp32 out.
__global__ __launch_bounds__(256) void gemm_bt(const unsigned short* __restrict__ A,
                                               const unsigned short* __restrict__ W,
                                               const float* __restrict__ bias,
                                               float* __restrict__ dst){
    const int mt = blockIdx.x, nt0 = blockIdx.y;
    const int wave = threadIdx.x >> 6, lane = threadIdx.x & 63;
    const int g = lane >> 4, r16 = lane & 15;
    const unsigned short* Ap = A + (size_t)(mt*64 + wave*16 + r16) * 512;

    f32x4 acc[4];
    #pragma unroll
    for (int i = 0; i < 4; ++i) acc[i] = (f32x4){0.f,0.f,0.f,0.f};

    #pragma unroll
    for (int k0 = 0; k0 < 512; k0 += 64){
        s16x8 a0 = *(const s16x8*)(Ap + k0 + g*8);
        s16x8 a1 = *(const s16x8*)(Ap + k0 + 32 + g*8);
        #pragma unroll
        for (int nt = 0; nt < 4; ++nt){
            const unsigned short* Wp = W + (size_t)(nt0*64 + nt*16 + r16)*512 + k0 + g*8;
            s16x8 b0 = *(const s16x8*)(Wp);
            s16x8 b1 = *(const s16x8*)(Wp + 32);
            acc[nt] = MFMA(a0, b0, acc[nt]);
            acc[nt] = MFMA(a1, b1, acc[nt]);
        }
    }

    #pragma unroll
    for (int nt = 0; nt < 4; ++nt){
        const float bv = bias[nt0*64 + nt*16 + r16];
        #pragma unroll
        for (int r = 0; r < 4; ++r){
            const int orow = mt*64 + wave*16 + g*4 + r;
            dst[(size_t)orow*512 + nt0*64 + nt*16 + r16] = acc[nt][r] + bv;
        }
    }
}

// Fused attention. Block = 128 q rows (8 waves x 16 rows) x all 4096 k.
// Pass 1: 3-deep K ring (counted vmcnt(1), no drains) -> rowsums of exp2.
// Pass 2: K/V double-buffered, recompute scores, stage P (bf16) 2 tiles deep
// per wave, 512B-contiguous NONTEMPORAL attn stores (A/B-verified: removing
// NT costs +81us -- L2 pollution evicts K/V working set), PV from LDS V tile.
__global__ __launch_bounds__(512, 4) void attn_fused(const unsigned short* __restrict__ qh,
                                                     const unsigned short* __restrict__ kh,
                                                     const unsigned short* __restrict__ vT,
                                                     float* __restrict__ attn,
                                                     unsigned short* __restrict__ ctx){
    __shared__ unsigned short Kb[3*64*64];              // 24 KB (ring-3 / dbuf slots 0,1)
    __shared__ unsigned short Vb[2][64][64];            // 16 KB
    __shared__ __align__(16) unsigned short Pbf[8][16][136];  // 34.8 KB (2-tile)

    // XCD-aware swizzle: 512 blocks, 8 XCDs, 64 consecutive per XCD
    const int lin = blockIdx.y * 32 + blockIdx.x;
    const int nl  = (lin & 7) * 64 + (lin >> 3);
    const int qt  = nl & 31;
    const int bh  = nl >> 5;

    const int wave = threadIdx.x >> 6, lane = threadIdx.x & 63;
    const int g = lane >> 4, r16 = lane & 15;

    const unsigned short* qbase = qh + (size_t)bh*S_*DH_;
    const unsigned short* kbase = kh + (size_t)bh*S_*DH_;
    const unsigned short* vbase = vT + (size_t)bh*DH_*S_;

    // staging: wave stages 8 rows; LDS linear, global source pre-swizzled
    const int tr = wave*8 + (lane >> 3);
    const int cc = (lane & 7) ^ (tr & 7);
    const int stg = tr*64 + (lane & 7)*8;        // LDS short-offset within a slot

    // read-side swizzled chunk offsets (row = nt*16 + r16 -> row&7 == r16&7)
    const int sw = r16 & 7;
    const int c0 = (g ^ sw) * 8;
    const int c1 = ((4 + g) ^ sw) * 8;

    // Q fragment (16 q rows per wave)
    const int qrow = qt*128 + wave*16 + r16;
    s16x8 qa0 = *(const s16x8*)(qbase + (size_t)qrow*DH_ + g*8);
    s16x8 qa1 = *(const s16x8*)(qbase + (size_t)qrow*DH_ + 32 + g*8);

    // ---- pass 1: row sums, 3-deep ring ----
    GLDS(kbase + (size_t)tr*DH_ + cc*8,          Kb + 0*4096 + stg);
    GLDS(kbase + (size_t)(64 + tr)*DH_ + cc*8,   Kb + 1*4096 + stg);

    float lsum[4] = {0.f,0.f,0.f,0.f};
    for (int t = 0; t < 64; ++t){
        if (t == 63) asm volatile("s_waitcnt vmcnt(0)" ::: "memory");
        else         asm volatile("s_waitcnt vmcnt(1)" ::: "memory");
        __builtin_amdgcn_s_barrier();
        __builtin_amdgcn_sched_barrier(0);
        if (t < 62){
            const int s2 = (t + 2) % 3;
            GLDS(kbase + (size_t)((t+2)*64 + tr)*DH_ + cc*8, Kb + s2*4096 + stg);
        }
        __builtin_amdgcn_sched_barrier(0);
        const unsigned short* Kt = Kb + (t % 3)*4096;
        #pragma unroll
        for (int nt = 0; nt < 4; ++nt){
            const int row = nt*16 + r16;
            s16x8 b0 = *(const s16x8*)(Kt + row*64 + c0);
            s16x8 b1 = *(const s16x8*)(Kt + row*64 + c1);
            f32x4 acc = (f32x4){0.f,0.f,0.f,0.f};
            acc = MFMA(qa0, b0, acc);
            acc = MFMA(qa1, b1, acc);
            #pragma unroll
            for (int r = 0; r < 4; ++r)
                lsum[r] += __builtin_amdgcn_exp2f(acc[r]*EXP_C);
        }
    }

    #pragma unroll
    for (int m = 1; m < 16; m <<= 1){
        #pragma unroll
        for (int r = 0; r < 4; ++r) lsum[r] += __shfl_xor(lsum[r], m, 64);
    }
    float inv[4];
    #pragma unroll
    for (int r = 0; r < 4; ++r) inv[r] = 1.0f / lsum[r];

    // ---- handoff: restage K0 + V0 ----
    __builtin_amdgcn_s_barrier();
    __builtin_amdgcn_sched_barrier(0);
    GLDS(kbase + (size_t)tr*DH_ + cc*8, Kb + 0*4096 + stg);
    GLDS(vbase + (size_t)tr*S_  + cc*8, &Vb[0][0][0] + stg);
    asm volatile("s_waitcnt vmcnt(0)" ::: "memory");
    __builtin_amdgcn_s_barrier();
    __builtin_amdgcn_sched_barrier(0);

    // ---- pass 2 ----
    f32x4 oacc[4];
    #pragma unroll
    for (int i = 0; i < 4; ++i) oacc[i] = (f32x4){0.f,0.f,0.f,0.f};

    float* attnW = attn + ((size_t)bh*S_ + qt*128 + wave*16)*S_;
    unsigned short (*Pw)[136] = Pbf[wave];
    const int sl = lane & 31, sh = lane >> 5;

    auto compute_tile = [&](int t){
        const unsigned short* Kt = Kb + (t&1)*4096;
        const unsigned short (*Vt)[64] = Vb[t&1];
        const int cb = (t&1)*64;
        f32x4 pacc[4];
        #pragma unroll
        for (int nt = 0; nt < 4; ++nt){
            const int row = nt*16 + r16;
            s16x8 b0 = *(const s16x8*)(Kt + row*64 + c0);
            s16x8 b1 = *(const s16x8*)(Kt + row*64 + c1);
            f32x4 acc = (f32x4){0.f,0.f,0.f,0.f};
            acc = MFMA(qa0, b0, acc);
            acc = MFMA(qa1, b1, acc);
            pacc[nt] = acc;
        }
        #pragma unroll
        for (int nt = 0; nt < 4; ++nt){
            #pragma unroll
            for (int r = 0; r < 4; ++r){
                float p = __builtin_amdgcn_exp2f(pacc[nt][r]*EXP_C) * inv[r];
                Pw[g*4 + r][cb + nt*16 + r16] = f2bf(p);
            }
        }
        s16x8 pa0 = *(const s16x8*)(&Pw[r16][cb + g*8]);
        s16x8 pa1 = *(const s16x8*)(&Pw[r16][cb + 32 + g*8]);
        #pragma unroll
        for (int nt = 0; nt < 4; ++nt){
            const int row = nt*16 + r16;
            s16x8 v0 = *(const s16x8*)(&Vt[row][c0]);
            s16x8 v1 = *(const s16x8*)(&Vt[row][c1]);
            oacc[nt] = MFMA(pa0, v0, oacc[nt]);
            oacc[nt] = MFMA(pa1, v1, oacc[nt]);
        }
    };

    auto store_pair = [&](int tfirst){   // stores tiles (tfirst, tfirst+1)
        #pragma unroll
        for (int i = 0; i < 8; ++i){
            const int row = i*2 + sh;
            s16x4 pb = *(const s16x4*)(&Pw[row][sl*4]);
            f32x4 o;
            #pragma unroll
            for (int j = 0; j < 4; ++j) o[j] = bf2f((unsigned short)pb[j]);
            __builtin_nontemporal_store(o,
                (f32x4*)(attnW + (size_t)row*S_ + tfirst*64 + sl*4));
        }
    };

    // t = 0 (peeled: no stores, full drain)
    GLDS(kbase + (size_t)(1*64 + tr)*DH_ + cc*8, Kb + 1*4096 + stg);
    GLDS(vbase + (size_t)tr*S_ + 1*64 + cc*8,    &Vb[1][0][0] + stg);
    __builtin_amdgcn_sched_barrier(0);
    compute_tile(0);
    asm volatile("s_waitcnt vmcnt(0)" ::: "memory");
    __builtin_amdgcn_s_barrier();
    __builtin_amdgcn_sched_barrier(0);

    for (int t = 1; t < 64; ++t){
        const int nxt = (t + 1) & 63;
        GLDS(kbase + (size_t)(nxt*64 + tr)*DH_ + cc*8, Kb + ((t&1)^1)*4096 + stg);
        GLDS(vbase + (size_t)tr*S_ + nxt*64 + cc*8,    &Vb[(t&1)^1][0][0] + stg);
        __builtin_amdgcn_sched_barrier(0);
        if ((t & 1) == 0){
            store_pair(t - 2);
            __builtin_amdgcn_sched_barrier(0);
        }
        compute_tile(t);
        if (t & 1){
            asm volatile("s_waitcnt vmcnt(0)" ::: "memory");
        } else {
            asm volatile("s_waitcnt vmcnt(8)" ::: "memory");
        }
        __builtin_amdgcn_s_barrier();
        __builtin_amdgcn_sched_barrier(0);
    }
    store_pair(62);

    const int b = bh >> 3, h = bh & 7;
    #pragma unroll
    for (int nt = 0; nt < 4; ++nt){
        #pragma unroll
        for (int r = 0; r < 4; ++r){
            const int qr = qt*128 + wave*16 + g*4 + r;
            ctx[(size_t)(b*S_ + qr)*D_ + h*64 + nt*16 + r16] = f2bf(oacc[nt][r]);
        }
    }
}

extern "C" void kernel_launch(void* const* d_in, const int* in_sizes, int n_in,
                              void* d_out, int out_size, void* d_ws, size_t ws_size,
                              hipStream_t stream){
    const float* Q  = (const float*)d_in[0];
    const float* Wq = (const float*)d_in[1];
    const float* bq = (const float*)d_in[2];
    const float* Wk = (const float*)d_in[3];
    const float* bk = (const float*)d_in[4];
    const float* Wv = (const float*)d_in[5];
    const float* bv = (const float*)d_in[6];
    const float* Wo = (const float*)d_in[7];
    const float* bo = (const float*)d_in[8];

    float* out  = (float*)d_out;                 // [2,4096,512]
    float* attn = out + (size_t)M_*D_;           // [2,8,4096,4096]

    // Pre-attention temporaries live INSIDE the attn output region (dead
    // before attn_fused overwrites it).
    unsigned short* Qbf = (unsigned short*)attn;             // 4.2M elems
    unsigned short* Wqb = Qbf + (size_t)M_*D_;
    unsigned short* Wkb = Wqb + 512*512;
    unsigned short* Wvb = Wkb + 512*512;

    // Persistent scratch in d_ws
    unsigned short* qhb = (unsigned short*)d_ws;             // [BH][S][64]
    unsigned short* khb = qhb + (size_t)BH_*S_*DH_;
    unsigned short* vTb = khb + (size_t)BH_*S_*DH_;          // [BH][64][S]
    unsigned short* ctx = vTb + (size_t)BH_*S_*DH_;          // [M_][512] bf16
    unsigned short* Wob = ctx + (size_t)M_*D_;               // survives attn_fused

    cvt_all<<<dim3(5120), 256, 0, stream>>>(Q, Wq, Wk, Wv, Wo, Qbf, Wqb, Wkb, Wvb, Wob);

    gemm_qkv<<<dim3(M_/64, 8), 256, 0, stream>>>(Qbf, Wqb, bq, Wkb, bk, Wvb, bv,
                                                 qhb, khb, vTb);

    attn_fused<<<dim3(32, BH_), 512, 0, stream>>>(qhb, khb, vTb, attn, ctx);

    gemm_bt<<<dim3(M_/64, D_/64), 256, 0, stream>>>(ctx, Wob, bo, out);
}